// Round 1
// baseline (685.802 us; speedup 1.0000x reference)
//
#include <hip/hip_runtime.h>

#define SLEN  2048
#define BATCH 4096

__device__ __forceinline__ float fsigmoid(float xx) {
    // 1/(1+e^-x) = rcp(1 + 2^(-x*log2e))
    float t = __builtin_amdgcn_exp2f(-1.4426950408889634f * xx);
    return __builtin_amdgcn_rcpf(1.0f + t);
}
__device__ __forceinline__ float ftanh(float xx) {
    // tanh(x) = 1 - 2/(1 + e^(2x))
    float t = __builtin_amdgcn_exp2f(2.8853900817779268f * xx);
    return fmaf(-2.0f, __builtin_amdgcn_rcpf(1.0f + t), 1.0f);
}

extern "C" __global__ __launch_bounds__(256, 1)
void bilstm_kernel(const float* __restrict__ x,
                   const float* __restrict__ w_ih_f, const float* __restrict__ w_hh_f,
                   const float* __restrict__ b_ih_f, const float* __restrict__ b_hh_f,
                   const float* __restrict__ w_ih_b, const float* __restrict__ w_hh_b,
                   const float* __restrict__ b_ih_b, const float* __restrict__ b_hh_b,
                   const float* __restrict__ w_out, const float* __restrict__ b_out,
                   const int* __restrict__ future_p,
                   float* __restrict__ out)
{
    const int tid  = threadIdx.x;
    const int wv   = tid >> 6;     // wave in block (0..3)
    const int lane = tid & 63;
    const int e    = lane >> 4;    // batch elem within wave (0..3)
    const int r    = lane & 15;
    const int d    = r >> 3;       // 0 = fwd, 1 = bwd
    const int j    = r & 7;        // hidden index
    const int b    = blockIdx.x * 16 + wv * 4 + e;

    const float* wih_p = d ? w_ih_b : w_ih_f;
    const float* whh_p = d ? w_hh_b : w_hh_f;
    const float* bih_p = d ? b_ih_b : b_ih_f;
    const float* bhh_p = d ? b_hh_b : b_hh_f;

    // per-lane weights: rows {j, 8+j, 16+j, 24+j} of W_hh (gate order i,f,g,o)
    float whh[4][8], wih[4], bias[4];
    #pragma unroll
    for (int gi = 0; gi < 4; ++gi) {
        const int row = gi * 8 + j;
        float4 lo = *reinterpret_cast<const float4*>(whh_p + row * 8);
        float4 hi = *reinterpret_cast<const float4*>(whh_p + row * 8 + 4);
        whh[gi][0] = lo.x; whh[gi][1] = lo.y; whh[gi][2] = lo.z; whh[gi][3] = lo.w;
        whh[gi][4] = hi.x; whh[gi][5] = hi.y; whh[gi][6] = hi.z; whh[gi][7] = hi.w;
        wih[gi]  = wih_p[row];
        bias[gi] = bih_p[row] + bhh_p[row];
    }
    const float wout = w_out[d * 8 + j];
    const float bout = b_out[0];
    const int   fut  = future_p[0];

    __shared__ float h_lds[4][4][2][8];   // [wave][elem][dir][j]
    __shared__ float o_lds[4][4][32];     // [wave][elem][step mod 32]

    h_lds[wv][e][d][j] = 0.0f;
    __builtin_amdgcn_wave_barrier();

    float c = 0.0f;

    // x fetch: fwd step i reads x[i], bwd reads x[(future - i) mod S]
    auto ld_x = [&](int i) -> float {
        int row = d ? ((fut - i) & (SLEN - 1)) : i;
        return x[row * BATCH + b];
    };

    float xv[8], xn[8];
    #pragma unroll
    for (int u = 0; u < 8; ++u) xv[u] = ld_x(u);

    for (int t0 = 0; t0 < SLEN; t0 += 8) {
        const bool pf = (t0 + 8) < SLEN;
        if (pf) {
            #pragma unroll
            for (int u = 0; u < 8; ++u) xn[u] = ld_x(t0 + 8 + u);
        }
        #pragma unroll
        for (int u = 0; u < 8; ++u) {
            // read full h vector for this (elem, dir) from LDS (broadcast reads)
            float4 h03 = *reinterpret_cast<const float4*>(&h_lds[wv][e][d][0]);
            float4 h47 = *reinterpret_cast<const float4*>(&h_lds[wv][e][d][4]);
            float hh[8] = {h03.x, h03.y, h03.z, h03.w, h47.x, h47.y, h47.z, h47.w};

            float g0 = fmaf(xv[u], wih[0], bias[0]);
            float g1 = fmaf(xv[u], wih[1], bias[1]);
            float g2 = fmaf(xv[u], wih[2], bias[2]);
            float g3 = fmaf(xv[u], wih[3], bias[3]);
            #pragma unroll
            for (int k = 0; k < 8; ++k) {
                g0 = fmaf(hh[k], whh[0][k], g0);
                g1 = fmaf(hh[k], whh[1][k], g1);
                g2 = fmaf(hh[k], whh[2][k], g2);
                g3 = fmaf(hh[k], whh[3][k], g3);
            }
            float ia = fsigmoid(g0);
            float fa = fsigmoid(g1);
            float ga = ftanh(g2);
            float oa = fsigmoid(g3);
            c = fmaf(fa, c, ia * ga);
            float hn = oa * ftanh(c);

            __builtin_amdgcn_wave_barrier();
            h_lds[wv][e][d][j] = hn;      // publish h_j for next step
            __builtin_amdgcn_wave_barrier();

            // output: sum over the 16 lanes of this elem (both dirs)
            float p = hn * wout;
            p += __shfl_xor(p, 1);
            p += __shfl_xor(p, 2);
            p += __shfl_xor(p, 4);
            p += __shfl_xor(p, 8);
            if (r == 0) o_lds[wv][e][(t0 + u) & 31] = p;
        }
        // coalesced flush of 32 outputs per elem
        if ((t0 & 31) == 24) {
            __builtin_amdgcn_wave_barrier();
            const int le = lane >> 4, lo = lane & 15;
            const int bb = blockIdx.x * 16 + wv * 4 + le;
            const int s0 = t0 - 24;
            float v0 = o_lds[wv][le][lo];
            float v1 = o_lds[wv][le][lo + 16];
            out[bb * SLEN + s0 + lo]      = v0 + bout;
            out[bb * SLEN + s0 + 16 + lo] = v1 + bout;
        }
        if (pf) {
            #pragma unroll
            for (int u = 0; u < 8; ++u) xv[u] = xn[u];
        }
    }
}

extern "C" void kernel_launch(void* const* d_in, const int* in_sizes, int n_in,
                              void* d_out, int out_size, void* d_ws, size_t ws_size,
                              hipStream_t stream) {
    const float* xp     = (const float*)d_in[0];
    const float* wihf   = (const float*)d_in[1];
    const float* whhf   = (const float*)d_in[2];
    const float* bihf   = (const float*)d_in[3];
    const float* bhhf   = (const float*)d_in[4];
    const float* wihb   = (const float*)d_in[5];
    const float* whhb   = (const float*)d_in[6];
    const float* bihb   = (const float*)d_in[7];
    const float* bhhb   = (const float*)d_in[8];
    const float* wo     = (const float*)d_in[9];
    const float* bo     = (const float*)d_in[10];
    const int*   futp   = (const int*)d_in[11];
    float*       outp   = (float*)d_out;

    dim3 grid(BATCH / 16);
    dim3 block(256);
    hipLaunchKernelGGL(bilstm_kernel, grid, block, 0, stream,
                       xp, wihf, whhf, bihf, bhhf, wihb, whhb, bihb, bhhb,
                       wo, bo, futp, outp);
}

// Round 2
// 453.673 us; speedup vs baseline: 1.5117x; 1.5117x over previous
//
#include <hip/hip_runtime.h>

#define SLEN  2048
#define BATCH 4096

// DPP cross-lane move (VALU-speed, no LDS/lgkm).
template<int CTRL>
__device__ __forceinline__ float dppf(float v) {
    return __int_as_float(
        __builtin_amdgcn_update_dpp(0, __float_as_int(v), CTRL, 0xF, 0xF, true));
}
#define DPP_XOR1 0xB1   // quad_perm [1,0,3,2]
#define DPP_XOR2 0x4E   // quad_perm [2,3,0,1]
#define DPP_XOR7 0x141  // ROW_HALF_MIRROR (i ^ 7 within 8)
#define DPP_XOR8 0x128  // ROW_ROR:8 (i ^ 8 within 16)

__device__ __forceinline__ float fsigmoid(float xx) {
    float t = __builtin_amdgcn_exp2f(-1.4426950408889634f * xx);
    return __builtin_amdgcn_rcpf(1.0f + t);
}
__device__ __forceinline__ float ftanh(float xx) {
    // tanh(x) = 2*sigmoid(2x) - 1
    float t = __builtin_amdgcn_exp2f(-2.8853900817779268f * xx);
    return fmaf(2.0f, __builtin_amdgcn_rcpf(1.0f + t), -1.0f);
}

extern "C" __global__ __launch_bounds__(256, 1)
void bilstm_kernel(const float* __restrict__ x,
                   const float* __restrict__ w_ih_f, const float* __restrict__ w_hh_f,
                   const float* __restrict__ b_ih_f, const float* __restrict__ b_hh_f,
                   const float* __restrict__ w_ih_b, const float* __restrict__ w_hh_b,
                   const float* __restrict__ b_ih_b, const float* __restrict__ b_hh_b,
                   const float* __restrict__ w_out, const float* __restrict__ b_out,
                   const int* __restrict__ future_p,
                   float* __restrict__ out)
{
    const int tid  = threadIdx.x;
    const int wv   = tid >> 6;     // wave in block (0..3)
    const int lane = tid & 63;
    const int e    = lane >> 4;    // batch elem within wave (0..3)
    const int r    = lane & 15;
    const int d    = r >> 3;       // 0 = fwd, 1 = bwd
    const int j    = r & 7;        // hidden index
    const int b    = blockIdx.x * 16 + wv * 4 + e;

    const float* wih_p = d ? w_ih_b : w_ih_f;
    const float* whh_p = d ? w_hh_b : w_hh_f;
    const float* bih_p = d ? b_ih_b : b_ih_f;
    const float* bhh_p = d ? b_hh_b : b_hh_f;

    // Butterfly gather slot -> xor mask: {0,1,2,3,7,6,5,4}.
    // Weights are loaded permuted so the dot pairs slot m with h[j ^ M[m]].
    const int M[8] = {0, 1, 2, 3, 7, 6, 5, 4};
    float whh[4][8], wih[4], bias[4];
    #pragma unroll
    for (int gi = 0; gi < 4; ++gi) {
        const int row = gi * 8 + j;   // gate order i,f,g,o
        #pragma unroll
        for (int m = 0; m < 8; ++m)
            whh[gi][m] = whh_p[row * 8 + (j ^ M[m])];
        wih[gi]  = wih_p[row];
        bias[gi] = bih_p[row] + bhh_p[row];
    }
    const float wout = w_out[d * 8 + j];
    const float bout = b_out[0];
    const int   fut  = future_p[0];

    __shared__ float o_lds[4][4][33];   // [wave][elem][step mod 32] (+1 pad)

    float c  = 0.0f;
    float hn = 0.0f;

    auto ld_x = [&](int i) -> float {
        int row = d ? ((fut - i) & (SLEN - 1)) : i;
        return x[row * BATCH + b];
    };

    float xv[8], xn[8];
    #pragma unroll
    for (int u = 0; u < 8; ++u) xv[u] = ld_x(u);

    for (int t0 = 0; t0 < SLEN; t0 += 8) {
        const bool pf = (t0 + 8) < SLEN;
        if (pf) {
            #pragma unroll
            for (int u = 0; u < 8; ++u) xn[u] = ld_x(t0 + 8 + u);
        }
        #pragma unroll
        for (int u = 0; u < 8; ++u) {
            // all-gather h across the 8 lanes of this (elem, dir): 3 DPP stages
            float v0 = hn;                    // h[j]
            float a1 = dppf<DPP_XOR1>(v0);    // h[j^1]
            float b0 = dppf<DPP_XOR2>(v0);    // h[j^2]
            float b1 = dppf<DPP_XOR2>(a1);    // h[j^3]
            float c0 = dppf<DPP_XOR7>(v0);    // h[j^7]
            float c1 = dppf<DPP_XOR7>(a1);    // h[j^6]
            float c2 = dppf<DPP_XOR7>(b0);    // h[j^5]
            float c3 = dppf<DPP_XOR7>(b1);    // h[j^4]

            float g[4];
            #pragma unroll
            for (int gi = 0; gi < 4; ++gi) {
                float gx = fmaf(xv[u], wih[gi], bias[gi]);
                float s0 = fmaf(v0, whh[gi][0],
                           fmaf(a1, whh[gi][1],
                           fmaf(b0, whh[gi][2],
                           fmaf(b1, whh[gi][3], gx))));
                float s1 = fmaf(c0, whh[gi][4],
                           fmaf(c1, whh[gi][5],
                           fmaf(c2, whh[gi][6],
                                c3 * whh[gi][7])));
                g[gi] = s0 + s1;
            }
            float ia = fsigmoid(g[0]);
            float fa = fsigmoid(g[1]);
            float ga = ftanh(g[2]);
            float oa = fsigmoid(g[3]);
            c  = fmaf(fa, c, ia * ga);
            hn = oa * ftanh(c);

            // output: sum over 16 lanes (both dirs) via DPP butterfly adds
            float p = hn * wout;
            p += dppf<DPP_XOR1>(p);
            p += dppf<DPP_XOR2>(p);
            p += dppf<DPP_XOR7>(p);
            p += dppf<DPP_XOR8>(p);
            if (r == 0) o_lds[wv][e][(t0 + u) & 31] = p;
        }
        // coalesced flush of 32 outputs per elem
        if ((t0 & 31) == 24) {
            __builtin_amdgcn_wave_barrier();
            const int le = lane >> 4, lo = lane & 15;
            const int bb = blockIdx.x * 16 + wv * 4 + le;
            const int s0 = t0 - 24;
            float v0 = o_lds[wv][le][lo];
            float v1 = o_lds[wv][le][lo + 16];
            out[bb * SLEN + s0 + lo]      = v0 + bout;
            out[bb * SLEN + s0 + 16 + lo] = v1 + bout;
            __builtin_amdgcn_wave_barrier();
        }
        if (pf) {
            #pragma unroll
            for (int u = 0; u < 8; ++u) xv[u] = xn[u];
        }
    }
}

extern "C" void kernel_launch(void* const* d_in, const int* in_sizes, int n_in,
                              void* d_out, int out_size, void* d_ws, size_t ws_size,
                              hipStream_t stream) {
    const float* xp     = (const float*)d_in[0];
    const float* wihf   = (const float*)d_in[1];
    const float* whhf   = (const float*)d_in[2];
    const float* bihf   = (const float*)d_in[3];
    const float* bhhf   = (const float*)d_in[4];
    const float* wihb   = (const float*)d_in[5];
    const float* whhb   = (const float*)d_in[6];
    const float* bihb   = (const float*)d_in[7];
    const float* bhhb   = (const float*)d_in[8];
    const float* wo     = (const float*)d_in[9];
    const float* bo     = (const float*)d_in[10];
    const int*   futp   = (const int*)d_in[11];
    float*       outp   = (float*)d_out;

    dim3 grid(BATCH / 16);
    dim3 block(256);
    hipLaunchKernelGGL(bilstm_kernel, grid, block, 0, stream,
                       xp, wihf, whhf, bihf, bhhf, wihb, whhb, bihb, bhhb,
                       wo, bo, futp, outp);
}

// Round 3
// 371.531 us; speedup vs baseline: 1.8459x; 1.2211x over previous
//
#include <hip/hip_runtime.h>

#define SLEN  2048
#define BATCH 4096

// DPP cross-lane move (VALU-speed, no LDS/lgkm).
template<int CTRL>
__device__ __forceinline__ float dppf(float v) {
    return __int_as_float(
        __builtin_amdgcn_update_dpp(0, __float_as_int(v), CTRL, 0xF, 0xF, true));
}
#define DPP_XOR1 0xB1   // quad_perm [1,0,3,2]
#define DPP_XOR2 0x4E   // quad_perm [2,3,0,1]
#define DPP_XOR7 0x141  // ROW_HALF_MIRROR (i ^ 7 within 8)
#define DPP_XOR8 0x128  // ROW_ROR:8 (i ^ 8 within 16)

// packed fp32 FMA (VOP3P, full-rate dual f32) — operands are VGPR pairs
__device__ __forceinline__ float2 pkfma(float2 a, float2 b, float2 c) {
    float2 d;
    asm("v_pk_fma_f32 %0, %1, %2, %3" : "=v"(d) : "v"(a), "v"(b), "v"(c));
    return d;
}

__device__ __forceinline__ float fsigmoid(float xx) {
    float t = __builtin_amdgcn_exp2f(-1.4426950408889634f * xx);
    return __builtin_amdgcn_rcpf(1.0f + t);
}
__device__ __forceinline__ float ftanh(float xx) {
    // tanh(x) = 2*sigmoid(2x) - 1
    float t = __builtin_amdgcn_exp2f(-2.8853900817779268f * xx);
    return fmaf(2.0f, __builtin_amdgcn_rcpf(1.0f + t), -1.0f);
}

extern "C" __global__ __launch_bounds__(256, 1)
void bilstm_kernel(const float* __restrict__ x,
                   const float* __restrict__ w_ih_f, const float* __restrict__ w_hh_f,
                   const float* __restrict__ b_ih_f, const float* __restrict__ b_hh_f,
                   const float* __restrict__ w_ih_b, const float* __restrict__ w_hh_b,
                   const float* __restrict__ b_ih_b, const float* __restrict__ b_hh_b,
                   const float* __restrict__ w_out, const float* __restrict__ b_out,
                   const int* __restrict__ future_p,
                   float* __restrict__ out)
{
    const int tid  = threadIdx.x;
    const int wv   = tid >> 6;     // wave in block (0..3)
    const int lane = tid & 63;
    const int e    = lane >> 4;    // batch elem within wave (0..3)
    const int r    = lane & 15;
    const int d    = r >> 3;       // 0 = fwd, 1 = bwd
    const int j    = r & 7;        // hidden index
    const int b    = blockIdx.x * 16 + wv * 4 + e;

    const float* wih_p = d ? w_ih_b : w_ih_f;
    const float* whh_p = d ? w_hh_b : w_hh_f;
    const float* bih_p = d ? b_ih_b : b_ih_f;
    const float* bhh_p = d ? b_hh_b : b_hh_f;

    // Butterfly gather order (pairs): {j^0,j^1 | j^2,j^3 | j^7,j^6 | j^5,j^4}
    const int M[8] = {0, 1, 2, 3, 7, 6, 5, 4};
    float2 whh2[4][4], bini[4];
    float  wih[4];
    #pragma unroll
    for (int gi = 0; gi < 4; ++gi) {
        const int row = gi * 8 + j;   // gate order i,f,g,o
        #pragma unroll
        for (int p = 0; p < 4; ++p) {
            whh2[gi][p].x = whh_p[row * 8 + (j ^ M[2 * p])];
            whh2[gi][p].y = whh_p[row * 8 + (j ^ M[2 * p + 1])];
        }
        wih[gi]   = wih_p[row];
        bini[gi].x = bih_p[row] + bhh_p[row];   // bias folded into first pk_fma
        bini[gi].y = 0.0f;
    }
    const float wout = w_out[d * 8 + j];
    const float bout = b_out[0];
    const int   fut  = future_p[0];

    __shared__ float o_lds[4][4][2][33];   // [wave][elem][dir][step mod 32] (+pad)

    float c  = 0.0f;
    float hn = 0.0f;

    // x addressing: byte-voffset walks rows; x spans 2^25 bytes so the bwd
    // mod-S wrap is a simple mask (batch offset lives in the low 14 bits).
    const char* xb = (const char*)x;
    unsigned voff = ((unsigned)(d ? (fut & (SLEN - 1)) : 0) * BATCH + (unsigned)b) * 4u;
    const unsigned vdelta = d ? (unsigned)(-(BATCH * 4)) : (unsigned)(BATCH * 4);
    const unsigned vmask  = (unsigned)(SLEN * BATCH * 4 - 1);

    float xv[8], xn[8];
    #pragma unroll
    for (int u = 0; u < 8; ++u) {
        xv[u] = *(const float*)(xb + voff);
        voff = (voff + vdelta) & vmask;
    }

    for (int t0 = 0; t0 < SLEN; t0 += 8) {
        const bool pf = (t0 + 8) < SLEN;
        if (pf) {
            #pragma unroll
            for (int u = 0; u < 8; ++u) {
                xn[u] = *(const float*)(xb + voff);
                voff = (voff + vdelta) & vmask;
            }
        }
        #pragma unroll
        for (int u = 0; u < 8; ++u) {
            // all-gather h across the 8 lanes of this (elem, dir): 7 DPP, paired
            float2 P0, P1, P2, P3;
            P0.x = hn;                      // h[j]
            P0.y = dppf<DPP_XOR1>(hn);      // h[j^1]
            P1.x = dppf<DPP_XOR2>(P0.x);    // h[j^2]
            P1.y = dppf<DPP_XOR2>(P0.y);    // h[j^3]
            P2.x = dppf<DPP_XOR7>(P0.x);    // h[j^7]
            P2.y = dppf<DPP_XOR7>(P0.y);    // h[j^6]
            P3.x = dppf<DPP_XOR7>(P1.x);    // h[j^5]
            P3.y = dppf<DPP_XOR7>(P1.y);    // h[j^4]

            float g[4];
            #pragma unroll
            for (int gi = 0; gi < 4; ++gi) {
                float2 acc = pkfma(P0, whh2[gi][0], bini[gi]);
                acc = pkfma(P1, whh2[gi][1], acc);
                acc = pkfma(P2, whh2[gi][2], acc);
                acc = pkfma(P3, whh2[gi][3], acc);
                g[gi] = fmaf(xv[u], wih[gi], acc.x + acc.y);
            }
            float ia = fsigmoid(g[0]);
            float fa = fsigmoid(g[1]);
            float ga = ftanh(g[2]);
            float oa = fsigmoid(g[3]);
            c  = fmaf(fa, c, ia * ga);
            hn = oa * ftanh(c);

            // per-direction output partial: reduce over the 8 lanes of (e,d)
            float p = hn * wout;
            p += dppf<DPP_XOR1>(p);
            p += dppf<DPP_XOR2>(p);
            p += dppf<DPP_XOR7>(p);
            if ((r & 7) == 0) o_lds[wv][e][d][(t0 + u) & 31] = p;
        }
        // coalesced flush of 32 outputs per elem (sum dir partials here)
        if ((t0 & 31) == 24) {
            __builtin_amdgcn_wave_barrier();
            const int le = lane >> 4, lo = lane & 15;
            const int bb = blockIdx.x * 16 + wv * 4 + le;
            const int s0 = t0 - 24;
            float v0 = o_lds[wv][le][0][lo]      + o_lds[wv][le][1][lo];
            float v1 = o_lds[wv][le][0][lo + 16] + o_lds[wv][le][1][lo + 16];
            out[bb * SLEN + s0 + lo]      = v0 + bout;
            out[bb * SLEN + s0 + 16 + lo] = v1 + bout;
            __builtin_amdgcn_wave_barrier();
        }
        if (pf) {
            #pragma unroll
            for (int u = 0; u < 8; ++u) xv[u] = xn[u];
        }
    }
}

extern "C" void kernel_launch(void* const* d_in, const int* in_sizes, int n_in,
                              void* d_out, int out_size, void* d_ws, size_t ws_size,
                              hipStream_t stream) {
    const float* xp     = (const float*)d_in[0];
    const float* wihf   = (const float*)d_in[1];
    const float* whhf   = (const float*)d_in[2];
    const float* bihf   = (const float*)d_in[3];
    const float* bhhf   = (const float*)d_in[4];
    const float* wihb   = (const float*)d_in[5];
    const float* whhb   = (const float*)d_in[6];
    const float* bihb   = (const float*)d_in[7];
    const float* bhhb   = (const float*)d_in[8];
    const float* wo     = (const float*)d_in[9];
    const float* bo     = (const float*)d_in[10];
    const int*   futp   = (const int*)d_in[11];
    float*       outp   = (float*)d_out;

    dim3 grid(BATCH / 16);
    dim3 block(256);
    hipLaunchKernelGGL(bilstm_kernel, grid, block, 0, stream,
                       xp, wihf, whhf, bihf, bhhf, wihb, whhb, bihb, bhhb,
                       wo, bo, futp, outp);
}